// Round 1
// baseline (623.563 us; speedup 1.0000x reference)
//
#include <hip/hip_runtime.h>

#define B_ 256
#define T_ 512
#define N_ 128

typedef float v2f __attribute__((ext_vector_type(2)));

__device__ __forceinline__ float readlane_f(float v, int k) {
    return __int_as_float(__builtin_amdgcn_readlane(__float_as_int(v), k));
}

// One wave (64 threads) per batch element, 256 blocks = 1 block/CU.
// The whole 128-state alpha vector lives inside this single wave:
//   lane l holds alpha[l] (.x) and alpha[64+l] (.y).
// exp(transition) is held entirely in registers:
//   e2[k] = (exp(T[k][l]), exp(T[k][64+l]))  -> 256 regs (VGPR+AGPR unified).
// Per step: 128 v_readlane broadcasts + 128 v_pk_fma_f32.
// NO LDS, NO barriers, NO shfl on the recurrence critical path.
__global__ __launch_bounds__(64, 1) void crf_fused_kernel(
    const float* __restrict__ lp,      // [B,T,N]
    const float* __restrict__ trans,   // [N,N]
    const float* __restrict__ startt,  // [N]
    const float* __restrict__ endt,    // [N]
    const int*   __restrict__ target,  // [B,T]
    const int*   __restrict__ lengths, // [B]
    float*       __restrict__ out)     // [B]
{
    const int b = blockIdx.x;
    const int l = threadIdx.x;          // 0..63

    const float* lpb = lp + (size_t)b * (T_ * N_);
    const int len = lengths[b];         // in [256, 512]

    // ---- exp(transition) into registers (one-time, ~256 loads + 256 exps) ----
    v2f e2[N_];
    #pragma unroll
    for (int k = 0; k < N_; ++k) {
        e2[k] = (v2f){ __expf(trans[k * N_ + l]),
                       __expf(trans[k * N_ + 64 + l]) };
    }

    // ---- t = 0 alpha (exp domain) ----
    v2f alpha = (v2f){ __expf(startt[l]      + lpb[l]),
                       __expf(startt[64 + l] + lpb[64 + l]) };

    float Macc = 0.f;

    // emission prefetch pipeline, distance 3 (len >= 256, rows 1..3 in-bounds)
    v2f cur = { lpb[1 * N_ + l], lpb[1 * N_ + 64 + l] };
    v2f nx1 = { lpb[2 * N_ + l], lpb[2 * N_ + 64 + l] };
    v2f nx2 = { lpb[3 * N_ + l], lpb[3 * N_ + 64 + l] };

    for (int t = 1; t < len; ++t) {
        const int tp = min(t + 3, T_ - 1);          // clamp: always in-bounds
        v2f nn = { lpb[tp * N_ + l], lpb[tp * N_ + 64 + l] };

        // emission exps are off the post-contraction critical chain
        v2f eexp = { __expf(cur.x), __expf(cur.y) };

        // full 128-contraction via SGPR broadcast + packed FMA.
        // 4 independent accumulator chains (depth 32) hide FMA latency.
        v2f a0 = {0.f, 0.f}, a1 = {0.f, 0.f}, a2 = {0.f, 0.f}, a3 = {0.f, 0.f};
        #pragma unroll
        for (int k = 0; k < 64; k += 4) {
            float s0 = readlane_f(alpha.x, k);
            float s1 = readlane_f(alpha.x, k + 1);
            float s2 = readlane_f(alpha.x, k + 2);
            float s3 = readlane_f(alpha.x, k + 3);
            a0 = __builtin_elementwise_fma(e2[k],     (v2f){s0, s0}, a0);
            a1 = __builtin_elementwise_fma(e2[k + 1], (v2f){s1, s1}, a1);
            a2 = __builtin_elementwise_fma(e2[k + 2], (v2f){s2, s2}, a2);
            a3 = __builtin_elementwise_fma(e2[k + 3], (v2f){s3, s3}, a3);
        }
        #pragma unroll
        for (int k = 0; k < 64; k += 4) {
            float s0 = readlane_f(alpha.y, k);
            float s1 = readlane_f(alpha.y, k + 1);
            float s2 = readlane_f(alpha.y, k + 2);
            float s3 = readlane_f(alpha.y, k + 3);
            a0 = __builtin_elementwise_fma(e2[64 + k],     (v2f){s0, s0}, a0);
            a1 = __builtin_elementwise_fma(e2[64 + k + 1], (v2f){s1, s1}, a1);
            a2 = __builtin_elementwise_fma(e2[64 + k + 2], (v2f){s2, s2}, a2);
            a3 = __builtin_elementwise_fma(e2[64 + k + 3], (v2f){s3, s3}, a3);
        }
        v2f p = (a0 + a1) + (a2 + a3);

        if ((t & 3) == 0) {            // deferred rescale (wave-uniform)
            float sc  = readlane_f(p.x, 0);
            float isc = __builtin_amdgcn_rcpf(sc);
            p = p * (v2f){isc, isc};
            Macc += __logf(sc);
        }

        alpha = p * eexp;

        cur = nx1; nx1 = nx2; nx2 = nn;
    }

    // ---- log Z ----
    float f = alpha.x * __expf(endt[l]) + alpha.y * __expf(endt[64 + l]);
    #pragma unroll
    for (int off = 32; off > 0; off >>= 1) f += __shfl_xor(f, off);
    const float logZ = Macc + __logf(f);

    // ---- path score (gathers) ----
    const int* tg = target + b * T_;
    float acc = 0.f;
    for (int t = l; t < len; t += 64) {
        int c = tg[t];
        acc += lpb[t * N_ + c];
        if (t + 1 < len) acc += trans[c * N_ + tg[t + 1]];
    }
    #pragma unroll
    for (int off = 32; off > 0; off >>= 1) acc += __shfl_xor(acc, off);

    if (l == 0) out[b] = acc + startt[tg[0]] + endt[tg[len - 1]] - logZ;
}

extern "C" void kernel_launch(void* const* d_in, const int* in_sizes, int n_in,
                              void* d_out, int out_size, void* d_ws, size_t ws_size,
                              hipStream_t stream) {
    const float* lp     = (const float*)d_in[0];
    const float* trans  = (const float*)d_in[1];
    const float* st     = (const float*)d_in[2];
    const float* en     = (const float*)d_in[3];
    const int*   target = (const int*)d_in[4];
    const int*   lens   = (const int*)d_in[5];
    float* out = (float*)d_out;

    crf_fused_kernel<<<B_, 64, 0, stream>>>(lp, trans, st, en, target, lens, out);
}

// Round 2
// 325.615 us; speedup vs baseline: 1.9150x; 1.9150x over previous
//
#include <hip/hip_runtime.h>

#define B_ 256
#define T_ 512
#define N_ 128

typedef float v2f __attribute__((ext_vector_type(2)));

__device__ __forceinline__ float readlane_f(float v, int k) {
    return __int_as_float(__builtin_amdgcn_readlane(__float_as_int(v), k));
}

// Barrier that drains only LDS (lgkmcnt), NOT vmcnt: global emission
// prefetches stay in flight across it.
__device__ __forceinline__ void barrier_lds() {
    asm volatile("s_waitcnt lgkmcnt(0)\n\ts_barrier" ::: "memory");
}

// One chain per block, TWO waves per chain (256 blocks x 128 threads).
// Wave w owns contraction half i in [64w, 64w+64):
//   e2[k] = (exp(T[64w+k][l]), exp(T[64w+k][64+l]))  -> 128 VGPRs, resident.
// alpha is fully REPLICATED in both waves: lane l holds (alpha[l], alpha[64+l]).
// Broadcast source for wave w is its own register half (alpha.x or alpha.y):
//   64 v_readlane + 64 v_pk_fma_f32 per wave per step.
// Cross-wave cost per step: ONE ds_write_b64 + barrier + ONE ds_read_b64.
// No shfl on the critical path (the 4-wave version needed one per step).
__global__ __launch_bounds__(128, 1) void crf_fused_kernel(
    const float* __restrict__ lp,      // [B,T,N]
    const float* __restrict__ trans,   // [N,N]
    const float* __restrict__ startt,  // [N]
    const float* __restrict__ endt,    // [N]
    const int*   __restrict__ target,  // [B,T]
    const int*   __restrict__ lengths, // [B]
    float*       __restrict__ out)     // [B]
{
    const int b   = blockIdx.x;
    const int tid = threadIdx.x;
    const int w   = tid >> 6;          // wave 0/1 = i-half
    const int l   = tid & 63;

    __shared__ v2f  part[2][2][64];    // [parity][wave][lane]
    __shared__ float red[4];

    const float* lpb = lp + (size_t)b * (T_ * N_);
    const int len = lengths[b];        // in [256, 512]

    // ---- exp(transition) half into registers: 64 x v2f = 128 VGPRs ----
    v2f e2[64];
    {
        const float* tq = trans + (w << 6) * N_;
        #pragma unroll
        for (int k = 0; k < 64; ++k) {
            e2[k] = (v2f){ __expf(tq[k * N_ + l]),
                           __expf(tq[k * N_ + 64 + l]) };
        }
    }

    // ---- t = 0 alpha (exp domain), replicated in both waves ----
    v2f alpha = (v2f){ __expf(startt[l]      + lpb[l]),
                       __expf(startt[64 + l] + lpb[64 + l]) };

    float Macc = 0.f;

    // emission prefetch pipeline, distance 3 (len >= 256, rows 1..3 valid)
    v2f cur = { lpb[1 * N_ + l], lpb[1 * N_ + 64 + l] };
    v2f nx1 = { lpb[2 * N_ + l], lpb[2 * N_ + 64 + l] };
    v2f nx2 = { lpb[3 * N_ + l], lpb[3 * N_ + 64 + l] };

    for (int t = 1; t < len; ++t) {
        const int tp = min(t + 3, T_ - 1);          // clamp: always in-bounds
        v2f nn = { lpb[tp * N_ + l], lpb[tp * N_ + 64 + l] };

        // emission exps are off the post-combine critical chain
        v2f eexp = { __expf(cur.x), __expf(cur.y) };

        // this wave's broadcast source: its own half of the replicated alpha
        const float asrc = w ? alpha.y : alpha.x;

        // half-contraction: 64 readlane + 64 pk_fma, 4 independent chains
        v2f a0 = {0.f, 0.f}, a1 = {0.f, 0.f}, a2 = {0.f, 0.f}, a3 = {0.f, 0.f};
        #pragma unroll
        for (int k = 0; k < 64; k += 4) {
            float s0 = readlane_f(asrc, k);
            float s1 = readlane_f(asrc, k + 1);
            float s2 = readlane_f(asrc, k + 2);
            float s3 = readlane_f(asrc, k + 3);
            a0 = __builtin_elementwise_fma(e2[k],     (v2f){s0, s0}, a0);
            a1 = __builtin_elementwise_fma(e2[k + 1], (v2f){s1, s1}, a1);
            a2 = __builtin_elementwise_fma(e2[k + 2], (v2f){s2, s2}, a2);
            a3 = __builtin_elementwise_fma(e2[k + 3], (v2f){s3, s3}, a3);
        }
        v2f p = (a0 + a1) + (a2 + a3);

        // combine the two halves: one b64 write + barrier + one b64 read
        const int pb = t & 1;
        part[pb][w][l] = p;
        barrier_lds();
        v2f s = p + part[pb][w ^ 1][l];

        if ((t & 3) == 0) {            // deferred rescale (block-uniform)
            float sc  = readlane_f(s.x, 0);
            float isc = __builtin_amdgcn_rcpf(sc);
            s = s * (v2f){isc, isc};
            Macc += __logf(sc);
        }

        alpha = s * eexp;

        cur = nx1; nx1 = nx2; nx2 = nn;
    }

    // ---- log Z (wave 0's replica) ----
    if (w == 0) {
        float f = alpha.x * __expf(endt[l]) + alpha.y * __expf(endt[64 + l]);
        #pragma unroll
        for (int off = 32; off > 0; off >>= 1) f += __shfl_xor(f, off);
        if (l == 0) red[0] = Macc + __logf(f);
    }

    // ---- path score (gathers), all 128 threads ----
    const int* tg = target + b * T_;
    float acc = 0.f;
    for (int t = tid; t < len; t += 128) {
        int c = tg[t];
        acc += lpb[t * N_ + c];
        if (t + 1 < len) acc += trans[c * N_ + tg[t + 1]];
    }
    #pragma unroll
    for (int off = 32; off > 0; off >>= 1) acc += __shfl_xor(acc, off);
    if (l == 0) red[1 + w] = acc;
    __syncthreads();

    if (tid == 0) {
        float sc = red[1] + red[2];
        out[b] = sc + startt[tg[0]] + endt[tg[len - 1]] - red[0];
    }
}

extern "C" void kernel_launch(void* const* d_in, const int* in_sizes, int n_in,
                              void* d_out, int out_size, void* d_ws, size_t ws_size,
                              hipStream_t stream) {
    const float* lp     = (const float*)d_in[0];
    const float* trans  = (const float*)d_in[1];
    const float* st     = (const float*)d_in[2];
    const float* en     = (const float*)d_in[3];
    const int*   target = (const int*)d_in[4];
    const int*   lens   = (const int*)d_in[5];
    float* out = (float*)d_out;

    crf_fused_kernel<<<B_, 128, 0, stream>>>(lp, trans, st, en, target, lens, out);
}